// Round 8
// baseline (129.275 us; speedup 1.0000x reference)
//
#include <hip/hip_runtime.h>
#include <math.h>

// RESUS_NN_2327872274812: Q=8192, S=30, D=512.
// thread = (q_local 0..15, dseg 0..15): owns query q, d-slice [32*dseg, +32).
// - query + fc1_w slices loaded ONCE into 16 named float4 regs (per-thread
//   contiguous 128 B -> every 64B line fully consumed by one thread, L1-
//   absorbed; one-time). ZERO global loads in the s-loop — rounds 5-7 were
//   capped at ~32 cyc/instr by 655K hot-loop broadcast global loads.
// - support in LDS, 2 passes x 15 rows. Row = 16 segments x 36 floats
//   (32 data + 4 pad): read quad = (9*dseg + j) % 8 -> balanced, free.
// - per (s): 8 ds_read_b128 + 96 VALU + 2 ds-atomic partial adds.
// - epilogue: verified 32-lane shuffle softmax, 8 groups x 2 queries.

#define QN 8192
#define SN 30
#define DN 512
#define BLK 256
#define QT 16            // queries per block
#define SROW 572         // floats per LDS support row (15*36 + 32)
#define SCHUNK 15        // support rows per pass

__global__ __launch_bounds__(BLK, 2)
void resus_one(const float* __restrict__ query,      // [Q][D]
               const float* __restrict__ support,    // [S][D]
               const float* __restrict__ support_y,  // [S]
               const float* __restrict__ support_pr, // [S]
               const float* __restrict__ query_pr,   // [Q]
               const float* __restrict__ fc1_w,      // [D]
               const float* __restrict__ adj_scale,  // [30]
               const float* __restrict__ adj_bias,   // [30]
               const int*   __restrict__ num_samples,// [1]
               float* __restrict__ out)              // [2*Q]
{
    __shared__ float  sp[SCHUNK * SROW];   // 34,320 B
    __shared__ float2 part[QT * SN];       //  3,840 B

    const int tid  = threadIdx.x;
    const int ql   = tid & 15;             // query slot
    const int dseg = tid >> 4;             // 32-d segment
    const int q    = blockIdx.x * QT + ql;

    // zero partials
    {
        float* pf = reinterpret_cast<float*>(part);
        for (int i = tid; i < QT * SN * 2; i += BLK) pf[i] = 0.0f;
    }

    // ---- one-time: query + w slices into named regs (contiguous 128 B) ----
    const float* qp = query + (size_t)q * DN + dseg * 32;
    const float4 q0 = *reinterpret_cast<const float4*>(qp +  0);
    const float4 q1 = *reinterpret_cast<const float4*>(qp +  4);
    const float4 q2 = *reinterpret_cast<const float4*>(qp +  8);
    const float4 q3 = *reinterpret_cast<const float4*>(qp + 12);
    const float4 q4 = *reinterpret_cast<const float4*>(qp + 16);
    const float4 q5 = *reinterpret_cast<const float4*>(qp + 20);
    const float4 q6 = *reinterpret_cast<const float4*>(qp + 24);
    const float4 q7 = *reinterpret_cast<const float4*>(qp + 28);
    const float* wp = fc1_w + dseg * 32;
    const float4 w0 = *reinterpret_cast<const float4*>(wp +  0);
    const float4 w1 = *reinterpret_cast<const float4*>(wp +  4);
    const float4 w2 = *reinterpret_cast<const float4*>(wp +  8);
    const float4 w3 = *reinterpret_cast<const float4*>(wp + 12);
    const float4 w4 = *reinterpret_cast<const float4*>(wp + 16);
    const float4 w5 = *reinterpret_cast<const float4*>(wp + 20);
    const float4 w6 = *reinterpret_cast<const float4*>(wp + 24);
    const float4 w7 = *reinterpret_cast<const float4*>(wp + 28);

    const int sbase = dseg * 36;           // this thread's segment offset

#define ACC4(QV, WV, SV) { float d_; \
    d_ = (QV).x - (SV).x; sc = fmaf((WV).x, fabsf(d_), sc); sq = fmaf(d_, d_, sq); \
    d_ = (QV).y - (SV).y; sc = fmaf((WV).y, fabsf(d_), sc); sq = fmaf(d_, d_, sq); \
    d_ = (QV).z - (SV).z; sc = fmaf((WV).z, fabsf(d_), sc); sq = fmaf(d_, d_, sq); \
    d_ = (QV).w - (SV).w; sc = fmaf((WV).w, fabsf(d_), sc); sq = fmaf(d_, d_, sq); }

    for (int pass = 0; pass < 2; ++pass) {
        __syncthreads();   // part zeroed / previous pass fully consumed

        // ---- stage 15 support rows: coalesced read -> segmented LDS ----
        const float4* sg = reinterpret_cast<const float4*>(
            support + (size_t)pass * SCHUNK * DN);
        for (int i = tid; i < SCHUNK * 128; i += BLK) {
            const int row = i >> 7, c4 = i & 127;
            *reinterpret_cast<float4*>(
                sp + row * SROW + 36 * (c4 >> 3) + 4 * (c4 & 7)) = sg[i];
        }
        __syncthreads();

#pragma unroll 3
        for (int sl = 0; sl < SCHUNK; ++sl) {
            const float* sr = sp + sl * SROW + sbase;
            const float4 s0 = *reinterpret_cast<const float4*>(sr +  0);
            const float4 s1 = *reinterpret_cast<const float4*>(sr +  4);
            const float4 s2 = *reinterpret_cast<const float4*>(sr +  8);
            const float4 s3 = *reinterpret_cast<const float4*>(sr + 12);
            const float4 s4 = *reinterpret_cast<const float4*>(sr + 16);
            const float4 s5 = *reinterpret_cast<const float4*>(sr + 20);
            const float4 s6 = *reinterpret_cast<const float4*>(sr + 24);
            const float4 s7 = *reinterpret_cast<const float4*>(sr + 28);

            float sc = 0.0f, sq = 0.0f;
            ACC4(q0, w0, s0) ACC4(q1, w1, s1)
            ACC4(q2, w2, s2) ACC4(q3, w3, s3)
            ACC4(q4, w4, s4) ACC4(q5, w5, s5)
            ACC4(q6, w6, s6) ACC4(q7, w7, s7)

            const int sglob = pass * SCHUNK + sl;
            atomicAdd(&part[ql * SN + sglob].x, sc);
            atomicAdd(&part[ql * SN + sglob].y, sq);
        }
    }
#undef ACC4
    __syncthreads();   // all partials landed

    // ---- epilogue: 8 groups of 32 lanes; group g handles queries g, g+8 ----
    const int grp   = tid >> 5;
    const int s32   = tid & 31;
    const bool valid = (s32 < SN);

    float dy = 0.0f;
    if (valid)
        dy = support_y[s32] - 1.0f / (1.0f + expf(-support_pr[s32]));

    const int ns = num_samples[0];
    const float ascale = fabsf(adj_scale[ns - 1]);
    const float abias  = adj_bias[ns - 1];

#pragma unroll
    for (int it = 0; it < 2; ++it) {
        const int qloc = grp + 8 * it;
        const int qg   = blockIdx.x * QT + qloc;
        const float2 pr = part[qloc * SN + (valid ? s32 : 0)];

        float scv = valid ? pr.x : -1e30f;
        float ssv = valid ? pr.y : 0.0f;

        float m = scv;
#pragma unroll
        for (int off = 16; off >= 1; off >>= 1)
            m = fmaxf(m, __shfl_xor(m, off));

        float e   = valid ? expf(scv - m) : 0.0f;
        float den = e;
        float num = dy * e;
        float l2  = valid ? sqrtf(ssv) : 0.0f;
#pragma unroll
        for (int off = 16; off >= 1; off >>= 1) {
            den += __shfl_xor(den, off);
            num += __shfl_xor(num, off);
            l2  += __shfl_xor(l2,  off);
        }

        if (s32 == 0) {
            out[qg]      = num / den * ascale + abias + query_pr[qg];
            out[QN + qg] = l2 * (1.0f / (float)SN);
        }
    }
}

extern "C" void kernel_launch(void* const* d_in, const int* in_sizes, int n_in,
                              void* d_out, int out_size, void* d_ws, size_t ws_size,
                              hipStream_t stream)
{
    const float* query      = (const float*)d_in[0];
    const float* support    = (const float*)d_in[1];
    const float* support_y  = (const float*)d_in[2];
    const float* support_pr = (const float*)d_in[3];
    const float* query_pr   = (const float*)d_in[4];
    const float* fc1_w      = (const float*)d_in[5];
    // d_in[6] = fc1_b: cancels in softmax, unused
    const float* adj_scale  = (const float*)d_in[7];
    const float* adj_bias   = (const float*)d_in[8];
    const int*   num_s      = (const int*)d_in[9];
    float* out = (float*)d_out;

    dim3 grid(QN / QT);      // 512 blocks, 2 per CU -> 8 waves/CU
    hipLaunchKernelGGL(resus_one, grid, dim3(BLK), 0, stream,
                       query, support, support_y, support_pr, query_pr,
                       fc1_w, adj_scale, adj_bias, num_s, out);
}

// Round 10
// 105.097 us; speedup vs baseline: 1.2301x; 1.2301x over previous
//
#include <hip/hip_runtime.h>
#include <math.h>

// RESUS_NN_2327872274812: Q=8192, S=30, D=512.  FP32-exact.
// thread = (s 0..31, dseg 0..31):  s = support row (valid < 30),
// dseg = 16-float d-slice.  BLK = 1024 (16 waves), 1 block/CU, grid 256.
//  - support[s][16-slice] + fc1_w[16-slice] live in 32 REGISTERS per thread,
//    boot-loaded ONCE (support is 60 KB; one-time semi-coalesced reads).
//    Steady live set ~40 VGPR -> below the allocator-demotion line (r1/r2/r8).
//  - queries stream through a double-buffered LDS ring (8 q/batch, 4 batches),
//    staged by coalesced float4 loads issued BEFORE each batch's compute
//    (~1100 cyc) -> HBM latency hidden.  ZERO hot-loop global loads (r5-r7).
//  - query rows stored seg-padded (stride 20 floats per 16-float seg) ->
//    ds_read_b128 quad-starts spread, ~balanced banks.
//  - per (q, thread): 4 ds_read_b128 + 48 VALU + xor-shuffle reduce over dseg
//    (offsets 1..16 = lane bits 0..4, same s).  Lane dseg==0 writes
//    part[q][s] (single writer -> deterministic, no atomics).
//  - epilogue: 32 half-wave groups, one query each, verified shuffle softmax.

#define QN 8192
#define SN 30
#define DN 512
#define BLK 1024
#define QB 32            // queries per block
#define BATCH 8          // queries per staging batch
#define NB (QB / BATCH)  // 4 batches
#define QROW 640         // padded floats per query row (32 segs * 20)

__global__ __launch_bounds__(BLK, 4)
void resus_one(const float* __restrict__ query,      // [Q][D]
               const float* __restrict__ support,    // [S][D]
               const float* __restrict__ support_y,  // [S]
               const float* __restrict__ support_pr, // [S]
               const float* __restrict__ query_pr,   // [Q]
               const float* __restrict__ fc1_w,      // [D]
               const float* __restrict__ adj_scale,  // [30]
               const float* __restrict__ adj_bias,   // [30]
               const int*   __restrict__ num_samples,// [1]
               float* __restrict__ out)              // [2*Q]
{
    __shared__ float  qbuf[2][BATCH * QROW];  // 40,960 B
    __shared__ float2 part[QB * SN];          //  7,680 B

    const int tid  = threadIdx.x;
    const int s    = tid >> 5;               // 0..31 (valid < 30)
    const int dseg = tid & 31;               // 0..31
    const int srw  = (s < SN) ? s : 0;       // clamp; results discarded

    // ---- boot: support + w slices into NAMED registers (one-time) ----
    const float* sp = support + srw * DN + dseg * 16;
    const float4 sA = *reinterpret_cast<const float4*>(sp + 0);
    const float4 sB = *reinterpret_cast<const float4*>(sp + 4);
    const float4 sC = *reinterpret_cast<const float4*>(sp + 8);
    const float4 sD = *reinterpret_cast<const float4*>(sp + 12);
    const float* wp = fc1_w + dseg * 16;
    const float4 wA = *reinterpret_cast<const float4*>(wp + 0);
    const float4 wB = *reinterpret_cast<const float4*>(wp + 4);
    const float4 wC = *reinterpret_cast<const float4*>(wp + 8);
    const float4 wD = *reinterpret_cast<const float4*>(wp + 12);

    const size_t qblock0 = (size_t)blockIdx.x * QB;

    // staging dest for this thread: one float4 per batch
    const int qloc_st = tid >> 7;            // 0..7 (row in batch)
    const int c4      = tid & 127;           // float4 col in row
    const int dst_off = qloc_st * QROW + (c4 >> 2) * 20 + (c4 & 3) * 4;

    // ---- stage batch 0 ----
    float4 ld = reinterpret_cast<const float4*>(query + qblock0 * DN)[tid];
    *reinterpret_cast<float4*>(&qbuf[0][dst_off]) = ld;
    __syncthreads();

#define ACC4(QV, WV, SV) { float d_; \
    d_ = (QV).x - (SV).x; sc = fmaf((WV).x, fabsf(d_), sc); sq = fmaf(d_, d_, sq); \
    d_ = (QV).y - (SV).y; sc = fmaf((WV).y, fabsf(d_), sc); sq = fmaf(d_, d_, sq); \
    d_ = (QV).z - (SV).z; sc = fmaf((WV).z, fabsf(d_), sc); sq = fmaf(d_, d_, sq); \
    d_ = (QV).w - (SV).w; sc = fmaf((WV).w, fabsf(d_), sc); sq = fmaf(d_, d_, sq); }

    int cur = 0;
    for (int b = 0; b < NB; ++b) {
        // issue next batch's global load BEFORE compute (overlap)
        if (b + 1 < NB)
            ld = reinterpret_cast<const float4*>(
                query + (qblock0 + (size_t)(b + 1) * BATCH) * DN)[tid];

        const float* qbp = qbuf[cur];
#pragma unroll
        for (int ql = 0; ql < BATCH; ++ql) {
            const float* qs = qbp + ql * QROW + dseg * 20;
            const float4 qa = *reinterpret_cast<const float4*>(qs + 0);
            const float4 qb4 = *reinterpret_cast<const float4*>(qs + 4);
            const float4 qc = *reinterpret_cast<const float4*>(qs + 8);
            const float4 qd = *reinterpret_cast<const float4*>(qs + 12);

            float sc = 0.0f, sq = 0.0f;
            ACC4(qa, wA, sA) ACC4(qb4, wB, sB)
            ACC4(qc, wC, sC) ACC4(qd, wD, sD)

            // reduce over dseg (lane bits 0..4; same s)
#pragma unroll
            for (int off = 16; off >= 1; off >>= 1) {
                sc += __shfl_xor(sc, off);
                sq += __shfl_xor(sq, off);
            }
            if (dseg == 0 && s < SN)
                part[(b * BATCH + ql) * SN + s] = make_float2(sc, sq);
        }

        if (b + 1 < NB) {
            // store next batch into the OTHER buffer (no race with readers
            // of qbuf[cur]); barrier before anyone computes from it.
            *reinterpret_cast<float4*>(&qbuf[cur ^ 1][dst_off]) = ld;
            __syncthreads();
        }
        cur ^= 1;
    }
#undef ACC4
    __syncthreads();   // all part[] writes visible

    // ---- epilogue: 32 half-wave groups, group g = query g ----
    const int g   = tid >> 5;                // 0..31
    const int s32 = tid & 31;
    const bool valid = (s32 < SN);
    const float2 pr = part[g * SN + (valid ? s32 : 0)];

    float dy = 0.0f;
    if (valid)
        dy = support_y[s32] - 1.0f / (1.0f + expf(-support_pr[s32]));

    float scv = valid ? pr.x : -1e30f;
    float ssv = valid ? pr.y : 0.0f;

    float m = scv;
#pragma unroll
    for (int off = 16; off >= 1; off >>= 1)
        m = fmaxf(m, __shfl_xor(m, off));

    float e   = valid ? expf(scv - m) : 0.0f;
    float den = e;
    float num = dy * e;
    float l2  = valid ? sqrtf(ssv) : 0.0f;
#pragma unroll
    for (int off = 16; off >= 1; off >>= 1) {
        den += __shfl_xor(den, off);
        num += __shfl_xor(num, off);
        l2  += __shfl_xor(l2,  off);
    }

    if (s32 == 0) {
        const int q = (int)qblock0 + g;
        const int ns = num_samples[0];
        const float scale = fabsf(adj_scale[ns - 1]);
        const float bias  = adj_bias[ns - 1];
        out[q]      = num / den * scale + bias + query_pr[q];
        out[QN + q] = l2 * (1.0f / (float)SN);
    }
}

extern "C" void kernel_launch(void* const* d_in, const int* in_sizes, int n_in,
                              void* d_out, int out_size, void* d_ws, size_t ws_size,
                              hipStream_t stream)
{
    const float* query      = (const float*)d_in[0];
    const float* support    = (const float*)d_in[1];
    const float* support_y  = (const float*)d_in[2];
    const float* support_pr = (const float*)d_in[3];
    const float* query_pr   = (const float*)d_in[4];
    const float* fc1_w      = (const float*)d_in[5];
    // d_in[6] = fc1_b: cancels in softmax, unused
    const float* adj_scale  = (const float*)d_in[7];
    const float* adj_bias   = (const float*)d_in[8];
    const int*   num_s      = (const int*)d_in[9];
    float* out = (float*)d_out;

    dim3 grid(QN / QB);      // 256 blocks, 1 per CU, 16 waves = 4/SIMD
    hipLaunchKernelGGL(resus_one, grid, dim3(BLK), 0, stream,
                       query, support, support_y, support_pr, query_pr,
                       fc1_w, adj_scale, adj_bias, num_s, out);
}

// Round 11
// 100.560 us; speedup vs baseline: 1.2856x; 1.0451x over previous
//
#include <hip/hip_runtime.h>
#include <math.h>

// RESUS_NN_2327872274812: Q=8192, S=30, D=512.  FP32-exact, deterministic.
// r8 structure (the one with the minimal issue-count bill) + the fix for why
// r8 ran 56us: the compiler SANK the boot-loaded q/w registers back into the
// hot loop (VGPR_Count=56 -> per-s global reloads). Empty asm volatile pins
// force the 64 floats to stay VGPR-resident across the s-loop.
// thread = (ql 0..15, dseg 0..15): owns query ql's 32-float d-slice.
//  - q + w slices: 16 named float4s, loaded once, PINNED.
//  - support: LDS, 2 passes x 15 rows, seg-padded (36 f/seg) -> b128 reads
//    hit 4 distinct quads per instr (16-fold ql-broadcast is free).
//  - per (thread, s): 8 ds_read_b128 + 96 VALU. No hot-loop global loads,
//    no hot-loop shuffles (r10's 23us DS-chain mistake).
//  - dseg-combine: xor16+xor32 shuffles (4 dlocs in-wave), lane dloc==0
//    stores part[wv][ql][s] -- unique writer, no atomics, deterministic.
//  - epilogue: 4-term fixed-order cross-wave sum + verified shuffle softmax.

#define QN 8192
#define SN 30
#define DN 512
#define BLK 256
#define QT 16            // queries per block
#define SROW 572         // floats per LDS support row (15 segs*36 + 32)
#define SCHUNK 15        // support rows per pass
#define PSTR 31          // part row stride (float2), odd -> clean banks

__global__ __launch_bounds__(BLK, 2)
void resus_one(const float* __restrict__ query,      // [Q][D]
               const float* __restrict__ support,    // [S][D]
               const float* __restrict__ support_y,  // [S]
               const float* __restrict__ support_pr, // [S]
               const float* __restrict__ query_pr,   // [Q]
               const float* __restrict__ fc1_w,      // [D]
               const float* __restrict__ adj_scale,  // [30]
               const float* __restrict__ adj_bias,   // [30]
               const int*   __restrict__ num_samples,// [1]
               float* __restrict__ out)              // [2*Q]
{
    __shared__ float  sp[SCHUNK * SROW];      // 34,320 B
    __shared__ float2 part[4 * QT * PSTR];    // 15,872 B  [wave][ql][s]

    const int tid  = threadIdx.x;
    const int ql   = tid & 15;                // query slot
    const int dseg = tid >> 4;                // 32-float d-segment
    const int wv   = tid >> 6;                // wave 0..3 (dseg quarter)
    const int dloc = dseg & 3;                // dseg within wave
    const int q    = blockIdx.x * QT + ql;

    // ---- one-time: q + w slices into named regs, then PIN them ----
    const float* qp = query + (size_t)q * DN + dseg * 32;
    float4 q0 = *reinterpret_cast<const float4*>(qp +  0);
    float4 q1 = *reinterpret_cast<const float4*>(qp +  4);
    float4 q2 = *reinterpret_cast<const float4*>(qp +  8);
    float4 q3 = *reinterpret_cast<const float4*>(qp + 12);
    float4 q4 = *reinterpret_cast<const float4*>(qp + 16);
    float4 q5 = *reinterpret_cast<const float4*>(qp + 20);
    float4 q6 = *reinterpret_cast<const float4*>(qp + 24);
    float4 q7 = *reinterpret_cast<const float4*>(qp + 28);
    const float* wp = fc1_w + dseg * 32;
    float4 w0 = *reinterpret_cast<const float4*>(wp +  0);
    float4 w1 = *reinterpret_cast<const float4*>(wp +  4);
    float4 w2 = *reinterpret_cast<const float4*>(wp +  8);
    float4 w3 = *reinterpret_cast<const float4*>(wp + 12);
    float4 w4 = *reinterpret_cast<const float4*>(wp + 16);
    float4 w5 = *reinterpret_cast<const float4*>(wp + 20);
    float4 w6 = *reinterpret_cast<const float4*>(wp + 24);
    float4 w7 = *reinterpret_cast<const float4*>(wp + 28);

#define PIN4(V) asm volatile("" : "+v"((V).x), "+v"((V).y), "+v"((V).z), "+v"((V).w))
    PIN4(q0); PIN4(q1); PIN4(q2); PIN4(q3);
    PIN4(q4); PIN4(q5); PIN4(q6); PIN4(q7);
    PIN4(w0); PIN4(w1); PIN4(w2); PIN4(w3);
    PIN4(w4); PIN4(w5); PIN4(w6); PIN4(w7);
#undef PIN4

#define ACC4(QV, WV, SV) { float d_; \
    d_ = (QV).x - (SV).x; sc = fmaf((WV).x, fabsf(d_), sc); sq = fmaf(d_, d_, sq); \
    d_ = (QV).y - (SV).y; sc = fmaf((WV).y, fabsf(d_), sc); sq = fmaf(d_, d_, sq); \
    d_ = (QV).z - (SV).z; sc = fmaf((WV).z, fabsf(d_), sc); sq = fmaf(d_, d_, sq); \
    d_ = (QV).w - (SV).w; sc = fmaf((WV).w, fabsf(d_), sc); sq = fmaf(d_, d_, sq); }

    const int sbase = dseg * 36;

    for (int pass = 0; pass < 2; ++pass) {
        __syncthreads();   // previous pass fully consumed

        // ---- stage 15 support rows (coalesced read -> segmented LDS) ----
        const float4* sg = reinterpret_cast<const float4*>(
            support + (size_t)pass * SCHUNK * DN);
        for (int i = tid; i < SCHUNK * 128; i += BLK) {
            const int row = i >> 7, c4 = i & 127;
            *reinterpret_cast<float4*>(
                sp + row * SROW + 36 * (c4 >> 3) + 4 * (c4 & 7)) = sg[i];
        }
        __syncthreads();

#pragma unroll 5
        for (int sl = 0; sl < SCHUNK; ++sl) {
            const float* sr = sp + sl * SROW + sbase;
            const float4 s0 = *reinterpret_cast<const float4*>(sr +  0);
            const float4 s1 = *reinterpret_cast<const float4*>(sr +  4);
            const float4 s2 = *reinterpret_cast<const float4*>(sr +  8);
            const float4 s3 = *reinterpret_cast<const float4*>(sr + 12);
            const float4 s4 = *reinterpret_cast<const float4*>(sr + 16);
            const float4 s5 = *reinterpret_cast<const float4*>(sr + 20);
            const float4 s6 = *reinterpret_cast<const float4*>(sr + 24);
            const float4 s7 = *reinterpret_cast<const float4*>(sr + 28);

            float sc = 0.0f, sq = 0.0f;
            ACC4(q0, w0, s0) ACC4(q1, w1, s1)
            ACC4(q2, w2, s2) ACC4(q3, w3, s3)
            ACC4(q4, w4, s4) ACC4(q5, w5, s5)
            ACC4(q6, w6, s6) ACC4(q7, w7, s7)

            // combine the wave's 4 dlocs (lane bits 4,5): fixed order, exact
            sc += __shfl_xor(sc, 16); sq += __shfl_xor(sq, 16);
            sc += __shfl_xor(sc, 32); sq += __shfl_xor(sq, 32);

            if (dloc == 0) {   // lanes 0..15: unique writer per (wv, ql, s)
                const int sg_ = pass * SCHUNK + sl;
                part[(wv * QT + ql) * PSTR + sg_] = make_float2(sc, sq);
            }
        }
    }
#undef ACC4
    __syncthreads();   // all partials landed

    // ---- epilogue: 8 half-wave groups; group g = queries g, g+8 ----
    const int grp  = tid >> 5;
    const int s32  = tid & 31;
    const bool valid = (s32 < SN);
    const int  si  = valid ? s32 : 0;

    float dy = 0.0f;
    if (valid)
        dy = support_y[s32] - 1.0f / (1.0f + expf(-support_pr[s32]));

    const int ns = num_samples[0];
    const float ascale = fabsf(adj_scale[ns - 1]);
    const float abias  = adj_bias[ns - 1];

#pragma unroll
    for (int it = 0; it < 2; ++it) {
        const int qloc = grp + 8 * it;
        const int qg   = blockIdx.x * QT + qloc;

        // fixed-order 4-wave sum: deterministic fp32
        const float2 p0 = part[(0 * QT + qloc) * PSTR + si];
        const float2 p1 = part[(1 * QT + qloc) * PSTR + si];
        const float2 p2 = part[(2 * QT + qloc) * PSTR + si];
        const float2 p3 = part[(3 * QT + qloc) * PSTR + si];
        float scv = ((p0.x + p1.x) + p2.x) + p3.x;
        float ssv = ((p0.y + p1.y) + p2.y) + p3.y;

        if (!valid) { scv = -1e30f; ssv = 0.0f; }

        float m = scv;
#pragma unroll
        for (int off = 16; off >= 1; off >>= 1)
            m = fmaxf(m, __shfl_xor(m, off));

        float e   = valid ? expf(scv - m) : 0.0f;
        float den = e;
        float num = dy * e;
        float l2  = valid ? sqrtf(ssv) : 0.0f;
#pragma unroll
        for (int off = 16; off >= 1; off >>= 1) {
            den += __shfl_xor(den, off);
            num += __shfl_xor(num, off);
            l2  += __shfl_xor(l2,  off);
        }

        if (s32 == 0) {
            out[qg]      = num / den * ascale + abias + query_pr[qg];
            out[QN + qg] = l2 * (1.0f / (float)SN);
        }
    }
}

extern "C" void kernel_launch(void* const* d_in, const int* in_sizes, int n_in,
                              void* d_out, int out_size, void* d_ws, size_t ws_size,
                              hipStream_t stream)
{
    const float* query      = (const float*)d_in[0];
    const float* support    = (const float*)d_in[1];
    const float* support_y  = (const float*)d_in[2];
    const float* support_pr = (const float*)d_in[3];
    const float* query_pr   = (const float*)d_in[4];
    const float* fc1_w      = (const float*)d_in[5];
    // d_in[6] = fc1_b: cancels in softmax, unused
    const float* adj_scale  = (const float*)d_in[7];
    const float* adj_bias   = (const float*)d_in[8];
    const int*   num_s      = (const int*)d_in[9];
    float* out = (float*)d_out;

    dim3 grid(QN / QT);      // 512 blocks, 2 per CU
    hipLaunchKernelGGL(resus_one, grid, dim3(BLK), 0, stream,
                       query, support, support_y, support_pr, query_pr,
                       fc1_w, adj_scale, adj_bias, num_s, out);
}